// Round 21
// baseline (132.489 us; speedup 1.0000x reference)
//
#include <hip/hip_runtime.h>
#include <hip/hip_fp16.h>

#define N_NODES   40000
#define N_EDGES   640000
#define D         128
#define N_CLASSES 40
#define N_GRAPHS  128

#define SCAN_CHUNK 2048
#define SCAN_NB    ((N_NODES + SCAN_CHUNK - 1) / SCAN_CHUNK)   // 20

#define NB_H    128
#define CHUNK_H (N_EDGES / NB_H)        // 5000 (< 65536 so u16 counts can't overflow)
#define NWORDS  (N_NODES / 2)           // 20000 u32 words of packed u16 counters
#define DS_NB   ((NWORDS + 255) / 256)  // 79
#define BASE_NB ((N_NODES + 255) / 256) // 157

#define SP2_NPW   5                     // ceil(40000 / 8192) contiguous nodes per wave

typedef unsigned int uint;
typedef unsigned short u16;
typedef unsigned char u8;
typedef _Float16 f16x8 __attribute__((ext_vector_type(8)));
typedef float f32x4 __attribute__((ext_vector_type(4)));
typedef float f32x2 __attribute__((ext_vector_type(2)));

// ------ hist (blocks 0..255) + DISTRIBUTED fuse (blocks 256..384, one k each) ---
__global__ __launch_bounds__(1024) void k_histfuse(const int* __restrict__ src,
                                                   const int* __restrict__ dst,
                                                   uint* __restrict__ cntS,
                                                   uint* __restrict__ cntD,
                                                   const float* __restrict__ W2,
                                                   const float* __restrict__ b2,
                                                   const float* __restrict__ Wc,
                                                   float* __restrict__ Wfused,
                                                   float* __restrict__ bfused,
                                                   float* __restrict__ sums,
                                                   uint* __restrict__ blksum) {
    __shared__ uint h[NWORDS];          // 80 KB
    const int bg = blockIdx.x, t = threadIdx.x;
    if (bg >= 2 * NB_H) {
        // ---- fuse branch, one k-row per block (129 blocks, latency overlapped) --
        const int k = bg - 2 * NB_H;    // 0..128; 128 = b2 row
        if (k < N_GRAPHS && t < D) sums[k * D + t] = 0.f;
        if (k == 0 && t < 32) blksum[t] = 0;
        if (t < N_CLASSES) {
            const float* row = (k < D) ? &W2[k * D] : b2;
            float s = 0.f;
            #pragma unroll 8
            for (int j = 0; j < D; ++j) s += row[j] * Wc[j * N_CLASSES + t];
            if (k < D) Wfused[k * N_CLASSES + t] = s;
            else bfused[t] = s;
        }
        return;
    }
    const int b = (bg < NB_H) ? bg : bg - NB_H;
    const int* __restrict__ idx = (bg < NB_H) ? src : dst;
    uint* __restrict__ cnt = (bg < NB_H) ? cntS : cntD;
    for (int i = t; i < NWORDS; i += 1024) h[i] = 0;
    __syncthreads();
    const int base = b * CHUNK_H;
    for (int e = t; e < CHUNK_H; e += 1024) {
        int v = idx[base + e];
        atomicAdd(&h[v >> 1], 1u << ((v & 1) * 16));
    }
    __syncthreads();
    for (int i = t; i < NWORDS; i += 1024) cnt[(size_t)b * NWORDS + i] = h[i];
}

// ------ merged: blocks 0..78 = deg sums; 79..235 = per-chunk CSR deltas --------
__global__ __launch_bounds__(256) void k_degbase(const uint* __restrict__ cntS,
                                                 const uint* __restrict__ cntD,
                                                 uint* __restrict__ deg_out,
                                                 uint* __restrict__ deg_in,
                                                 uint* __restrict__ blksum,
                                                 u16* __restrict__ baseDelta) {
    __shared__ uint wsum[4];
    const int t = threadIdx.x;
    if (blockIdx.x < DS_NB) {
        const int w = blockIdx.x * 256 + t;
        uint tot = 0;
        if (w < NWORDS) {
            uint s0 = 0, s1 = 0, d0 = 0, d1 = 0;
            for (int bb = 0; bb < NB_H; ++bb) {
                uint cs = cntS[(size_t)bb * NWORDS + w];
                s0 += cs & 0xffffu; s1 += cs >> 16;
            }
            for (int bb = 0; bb < NB_H; ++bb) {
                uint cd = cntD[(size_t)bb * NWORDS + w];
                d0 += cd & 0xffffu; d1 += cd >> 16;
            }
            deg_out[2 * w] = s0; deg_out[2 * w + 1] = s1;
            deg_in[2 * w]  = d0; deg_in[2 * w + 1]  = d1;
            tot = d0 + d1;
        }
        #pragma unroll
        for (int off = 32; off > 0; off >>= 1) tot += __shfl_down(tot, off);
        if ((t & 63) == 0) wsum[t >> 6] = tot;
        __syncthreads();
        if (t == 0) atomicAdd(&blksum[blockIdx.x >> 2],
                              wsum[0] + wsum[1] + wsum[2] + wsum[3]);
        return;
    }
    // ---- base branch: within-node prefix over chunks (u16 deltas) ----
    int i = (blockIdx.x - DS_NB) * 256 + t;
    if (i >= N_NODES) return;
    uint run = 0;
    for (int b = 0; b < NB_H; ++b) {
        baseDelta[(size_t)b * N_NODES + i] = (u16)run;
        run += (cntD[(size_t)b * NWORDS + (i >> 1)] >> ((i & 1) * 16)) & 0xffffu;
    }
}

// ------ merged: blocks 0..19 = scan_c (offsets+bounds); 20..644 = MFMA gemm1 ----
// gemm1 epilogue emits fp8 e4m3 hW.
__global__ __launch_bounds__(256, 1) void k_scangemm(const uint* __restrict__ deg_in,
                                                     const uint* __restrict__ blksum,
                                                     uint* __restrict__ offsets,
                                                     const int* __restrict__ gid,
                                                     int* __restrict__ bounds,
                                                     const float* __restrict__ feat,
                                                     const float* __restrict__ W1,
                                                     const uint* __restrict__ deg_out,
                                                     u8* __restrict__ hW) {
    __shared__ uint wsum[4];
    const int t = threadIdx.x;
    if (blockIdx.x < SCAN_NB) {
        // ---------------- scan_c branch ----------------
        const int b = blockIdx.x;
        const int lane = t & 63, wave = t >> 6;
        uint basesum = 0;
        for (int q = 0; q < b; ++q) basesum += blksum[q];
        const int base = b * SCAN_CHUNK + t * 8;
        uint v[8];
        uint s = 0;
        #pragma unroll
        for (int j = 0; j < 8; ++j) {
            int idx = base + j;
            v[j] = (idx < N_NODES) ? deg_in[idx] : 0u;
            s += v[j];
        }
        uint inc = s;
        #pragma unroll
        for (int off = 1; off < 64; off <<= 1) {
            uint o = __shfl_up(inc, off);
            if (lane >= off) inc += o;
        }
        if (lane == 63) wsum[wave] = inc;
        __syncthreads();
        if (t < 4) {
            uint w = wsum[t];
            #pragma unroll
            for (int off = 1; off < 4; off <<= 1) {
                uint o = __shfl_up(w, off);
                if (t >= off) w += o;
            }
            wsum[t] = w;
        }
        __syncthreads();
        uint excl = inc - s + (wave ? wsum[wave - 1] : 0u) + basesum;
        #pragma unroll
        for (int j = 0; j < 8; ++j) {
            int idx = base + j;
            if (idx < N_NODES) offsets[idx] = excl;
            excl += v[j];
        }
        if (b == SCAN_NB - 1 && t == 255) offsets[N_NODES] = excl;
        for (int j = 0; j < 8; ++j) {
            int idx = base + j;
            if (idx >= N_NODES) break;
            int g = gid[idx];
            if (idx == 0) {
                for (int q = 0; q <= g; ++q) bounds[q] = 0;
            } else {
                int gp = gid[idx - 1];
                for (int q = gp + 1; q <= g; ++q) bounds[q] = idx;
            }
            if (idx == N_NODES - 1) {
                for (int q = g + 1; q <= N_GRAPHS; ++q) bounds[q] = N_NODES;
            }
        }
        return;
    }
    // ---------------- gemm1 branch ----------------
    const int wv = t >> 6, l = t & 63;
    const int kg = l >> 4;
    const int c  = l & 15;
    const int r0 = (blockIdx.x - SCAN_NB) * 64 + wv * 16;

    f16x8 B[4][8];
    #pragma unroll
    for (int ks = 0; ks < 4; ++ks) {
        #pragma unroll
        for (int nt = 0; nt < 8; ++nt) {
            const int kb = ks * 32 + kg * 8;
            const int col = nt * 16 + c;
            f16x8 b;
            #pragma unroll
            for (int i = 0; i < 8; ++i)
                b[i] = (_Float16)W1[(kb + i) * D + col];
            B[ks][nt] = b;
        }
    }

    f32x4 acc[8];
    #pragma unroll
    for (int nt = 0; nt < 8; ++nt) acc[nt] = (f32x4){0.f, 0.f, 0.f, 0.f};

    const int arow = r0 + c;
    #pragma unroll
    for (int ks = 0; ks < 4; ++ks) {
        const float4 q0 = *(const float4*)&feat[(size_t)arow * D + ks * 32 + kg * 8];
        const float4 q1 = *(const float4*)&feat[(size_t)arow * D + ks * 32 + kg * 8 + 4];
        f16x8 a;
        a[0] = (_Float16)q0.x; a[1] = (_Float16)q0.y;
        a[2] = (_Float16)q0.z; a[3] = (_Float16)q0.w;
        a[4] = (_Float16)q1.x; a[5] = (_Float16)q1.y;
        a[6] = (_Float16)q1.z; a[7] = (_Float16)q1.w;
        #pragma unroll
        for (int nt = 0; nt < 8; ++nt)
            acc[nt] = __builtin_amdgcn_mfma_f32_16x16x32_f16(a, B[ks][nt], acc[nt], 0, 0, 0);
    }

    const int rloc = kg * 4;
    float ns[4];
    #pragma unroll
    for (int r = 0; r < 4; ++r)
        ns[r] = rsqrtf(fmaxf((float)deg_out[r0 + rloc + r], 1.f));
    #pragma unroll
    for (int nt = 0; nt < 8; ++nt) {
        #pragma unroll
        for (int r = 0; r < 4; ++r) {
            float v = acc[nt][r] * ns[r];
            int pk = __builtin_amdgcn_cvt_pk_fp8_f32(v, v, 0, false);
            hW[(size_t)(r0 + rloc + r) * D + nt * 16 + c] = (u8)pk;
        }
    }
}

// ------ CSR place via LDS rank cursors (no global atomics) ------
__global__ __launch_bounds__(1024) void k_place(const int* __restrict__ src,
                                                const int* __restrict__ dst,
                                                const uint* __restrict__ offsets,
                                                const u16* __restrict__ baseDelta,
                                                int* __restrict__ csr) {
    __shared__ uint rk[NWORDS];         // 80 KB, packed u16 ranks
    const int b = blockIdx.x, t = threadIdx.x;
    for (int i = t; i < NWORDS; i += 1024) rk[i] = 0;
    __syncthreads();
    const int base = b * CHUNK_H;
    for (int e = t; e < CHUNK_H; e += 1024) {
        int d = dst[base + e];
        uint sh = (d & 1) * 16;
        uint old = atomicAdd(&rk[d >> 1], 1u << sh);
        uint r = (old >> sh) & 0xffffu;
        csr[offsets[d] + baseDelta[(size_t)b * N_NODES + d] + r] = src[base + e];
    }
}

// ------- SpMM layer 1: dword fp8 gather, 2 edges/wave-iteration ----------------
// lane = half*32 + col; half processes edges eb+half, eb+2+half, ...
__global__ __launch_bounds__(256) void k_spmm1(const u8* __restrict__ X,
                                               const int* __restrict__ csr_src,
                                               const uint* __restrict__ offsets,
                                               const uint* __restrict__ deg_out,
                                               const uint* __restrict__ deg_in,
                                               const float* __restrict__ b1,
                                               uint* __restrict__ outp) {
    const int lane = threadIdx.x & 63;
    const int half = lane >> 5;
    const int col  = lane & 31;
    const uint* __restrict__ X32 = (const uint*)X;   // row = 32 dwords (128 fp8)
    int gw = (blockIdx.x * blockDim.x + threadIdx.x) >> 6;
    int nw = (gridDim.x * blockDim.x) >> 6;
    for (int i = gw; i < N_NODES; i += nw) {
        uint e0 = offsets[i], e1 = offsets[i + 1];
        f32x2 accA = {0.f, 0.f}, accB = {0.f, 0.f};
        uint eb = e0;
        for (; eb + 8 <= e1; eb += 8) {
            int s0 = csr_src[eb + half];
            int s1 = csr_src[eb + 2 + half];
            int s2 = csr_src[eb + 4 + half];
            int s3 = csr_src[eb + 6 + half];
            uint p0 = X32[(size_t)s0 * 32 + col];
            uint p1 = X32[(size_t)s1 * 32 + col];
            uint p2 = X32[(size_t)s2 * 32 + col];
            uint p3 = X32[(size_t)s3 * 32 + col];
            accA += __builtin_amdgcn_cvt_pk_f32_fp8(p0, false)
                  + __builtin_amdgcn_cvt_pk_f32_fp8(p1, false)
                  + __builtin_amdgcn_cvt_pk_f32_fp8(p2, false)
                  + __builtin_amdgcn_cvt_pk_f32_fp8(p3, false);
            accB += __builtin_amdgcn_cvt_pk_f32_fp8(p0, true)
                  + __builtin_amdgcn_cvt_pk_f32_fp8(p1, true)
                  + __builtin_amdgcn_cvt_pk_f32_fp8(p2, true)
                  + __builtin_amdgcn_cvt_pk_f32_fp8(p3, true);
        }
        for (; eb < e1; eb += 2) {
            uint e = eb + half;
            if (e < e1) {
                int s = csr_src[e];
                uint p = X32[(size_t)s * 32 + col];
                accA += __builtin_amdgcn_cvt_pk_f32_fp8(p, false);
                accB += __builtin_amdgcn_cvt_pk_f32_fp8(p, true);
            }
        }
        // combine halves (uniform across wave)
        accA[0] += __shfl_xor(accA[0], 32);
        accA[1] += __shfl_xor(accA[1], 32);
        accB[0] += __shfl_xor(accB[0], 32);
        accB[1] += __shfl_xor(accB[1], 32);
        float nd = rsqrtf(fmaxf((float)deg_in[i], 1.f));
        float ns = rsqrtf(fmaxf((float)deg_out[i], 1.f));
        float4 bb = *(const float4*)&b1[col * 4];
        float r0 = fmaxf(accA[0] * nd + bb.x, 0.f) * ns;
        float r1 = fmaxf(accA[1] * nd + bb.y, 0.f) * ns;
        float r2 = fmaxf(accB[0] * nd + bb.z, 0.f) * ns;
        float r3 = fmaxf(accB[1] * nd + bb.w, 0.f) * ns;
        int pk = __builtin_amdgcn_cvt_pk_fp8_f32(r0, r1, 0, false);
        pk = __builtin_amdgcn_cvt_pk_fp8_f32(r2, r3, pk, true);
        if (half == 0) outp[(size_t)i * 32 + col] = (uint)pk;
    }
}

// ------- SpMM layer 2 (dword fp8 gather) fused with pooling --------------------
__global__ __launch_bounds__(256) void k_spmm2pool(const uint* __restrict__ X32,
                                                   const int* __restrict__ csr_src,
                                                   const uint* __restrict__ offsets,
                                                   const uint* __restrict__ deg_in,
                                                   const int* __restrict__ gid,
                                                   float* __restrict__ sums) {
    const int lane = threadIdx.x & 63;
    const int half = lane >> 5;
    const int col  = lane & 31;
    const int w = (blockIdx.x * blockDim.x + threadIdx.x) >> 6;
    int n0 = w * SP2_NPW;
    if (n0 >= N_NODES) return;
    int n1 = n0 + SP2_NPW; if (n1 > N_NODES) n1 = N_NODES;
    f32x2 segA = {0.f, 0.f}, segB = {0.f, 0.f};   // per-half partials (linear)
    int cur = gid[n0];
    for (int i = n0; i < n1; ++i) {
        int g = gid[i];
        if (g != cur) {
            float s0 = segA[0] + __shfl_xor(segA[0], 32);
            float s1 = segA[1] + __shfl_xor(segA[1], 32);
            float s2 = segB[0] + __shfl_xor(segB[0], 32);
            float s3 = segB[1] + __shfl_xor(segB[1], 32);
            if (half == 0) {
                atomicAdd(&sums[cur * D + col * 4 + 0], s0);
                atomicAdd(&sums[cur * D + col * 4 + 1], s1);
                atomicAdd(&sums[cur * D + col * 4 + 2], s2);
                atomicAdd(&sums[cur * D + col * 4 + 3], s3);
            }
            segA[0] = 0.f; segA[1] = 0.f; segB[0] = 0.f; segB[1] = 0.f;
            cur = g;
        }
        uint e0 = offsets[i], e1 = offsets[i + 1];
        f32x2 accA = {0.f, 0.f}, accB = {0.f, 0.f};
        uint eb = e0;
        for (; eb + 8 <= e1; eb += 8) {
            int s0 = csr_src[eb + half];
            int s1 = csr_src[eb + 2 + half];
            int s2 = csr_src[eb + 4 + half];
            int s3 = csr_src[eb + 6 + half];
            uint p0 = X32[(size_t)s0 * 32 + col];
            uint p1 = X32[(size_t)s1 * 32 + col];
            uint p2 = X32[(size_t)s2 * 32 + col];
            uint p3 = X32[(size_t)s3 * 32 + col];
            accA += __builtin_amdgcn_cvt_pk_f32_fp8(p0, false)
                  + __builtin_amdgcn_cvt_pk_f32_fp8(p1, false)
                  + __builtin_amdgcn_cvt_pk_f32_fp8(p2, false)
                  + __builtin_amdgcn_cvt_pk_f32_fp8(p3, false);
            accB += __builtin_amdgcn_cvt_pk_f32_fp8(p0, true)
                  + __builtin_amdgcn_cvt_pk_f32_fp8(p1, true)
                  + __builtin_amdgcn_cvt_pk_f32_fp8(p2, true)
                  + __builtin_amdgcn_cvt_pk_f32_fp8(p3, true);
        }
        for (; eb < e1; eb += 2) {
            uint e = eb + half;
            if (e < e1) {
                int s = csr_src[e];
                uint p = X32[(size_t)s * 32 + col];
                accA += __builtin_amdgcn_cvt_pk_f32_fp8(p, false);
                accB += __builtin_amdgcn_cvt_pk_f32_fp8(p, true);
            }
        }
        float nd = rsqrtf(fmaxf((float)deg_in[i], 1.f));
        segA += accA * nd;
        segB += accB * nd;
    }
    float s0 = segA[0] + __shfl_xor(segA[0], 32);
    float s1 = segA[1] + __shfl_xor(segA[1], 32);
    float s2 = segB[0] + __shfl_xor(segB[0], 32);
    float s3 = segB[1] + __shfl_xor(segB[1], 32);
    if (half == 0) {
        atomicAdd(&sums[cur * D + col * 4 + 0], s0);
        atomicAdd(&sums[cur * D + col * 4 + 1], s1);
        atomicAdd(&sums[cur * D + col * 4 + 2], s2);
        atomicAdd(&sums[cur * D + col * 4 + 3], s3);
    }
}

// ---------------- per-graph classifier matvec ----------------
__global__ __launch_bounds__(64) void k_out(const float* __restrict__ sums,
                                            const int* __restrict__ bounds,
                                            const float* __restrict__ Wfused,
                                            const float* __restrict__ bfused,
                                            const float* __restrict__ bc,
                                            float* __restrict__ out) {
    int g = blockIdx.x, c = threadIdx.x;
    if (c >= N_CLASSES) return;
    int cnt = bounds[g + 1] - bounds[g];
    float inv = (cnt > 0) ? 1.f / (float)cnt : 0.f;
    float s = 0.f;
    #pragma unroll 8
    for (int k = 0; k < D; ++k) s += sums[g * D + k] * Wfused[k * N_CLASSES + c];
    out[g * N_CLASSES + c] = s * inv + (cnt > 0 ? bfused[c] : 0.f) + bc[c];
}

extern "C" void kernel_launch(void* const* d_in, const int* in_sizes, int n_in,
                              void* d_out, int out_size, void* d_ws, size_t ws_size,
                              hipStream_t stream) {
    const float* feat = (const float*)d_in[0];
    const float* W1   = (const float*)d_in[1];
    const float* b1   = (const float*)d_in[2];
    const float* W2   = (const float*)d_in[3];
    const float* b2   = (const float*)d_in[4];
    const float* Wc   = (const float*)d_in[5];
    const float* bc   = (const float*)d_in[6];
    const int*   src  = (const int*)d_in[7];
    const int*   dst  = (const int*)d_in[8];
    const int*   gid  = (const int*)d_in[9];
    float* out = (float*)d_out;

    // Dispatch order: histfuse, degbase, scangemm(hW), place(csr),
    // spmm1(h1s), spmm2pool, out.
    // Aliasing: csr over cntS (cntS last read: degbase); h1s over cntD (cntD
    // last read: degbase). hW disjoint (written by scangemm, before place).
    char* w = (char*)d_ws;
    uint* deg_out = (uint*)w; w += (size_t)N_NODES * 4;
    uint* deg_in  = (uint*)w; w += (size_t)N_NODES * 4;
    uint* offsets = (uint*)w; w += (size_t)(N_NODES + 4) * 4;
    int*  bounds  = (int*)w;  w += 132 * 4;
    uint* blksum  = (uint*)w; w += 32 * 4;
    float* Wfused = (float*)w; w += (size_t)D * N_CLASSES * 4;
    float* bfused = (float*)w; w += 64 * 4;
    float* sums   = (float*)w; w += (size_t)N_GRAPHS * D * 4;
    char* regA = w; w += (size_t)NB_H * NWORDS * 4;                  // 10.24 MB
    uint* cntS  = (uint*)regA;
    int*  csr   = (int*)regA;        // 2.56 MB, lives after degbase
    char* regB = w; w += (size_t)NB_H * NWORDS * 4;                  // 10.24 MB
    uint* cntD  = (uint*)regB;
    uint* h1s   = (uint*)regB;       // fp8 dwords: 5.12 MB, lives after degbase
    u16* baseDelta = (u16*)w; w += (size_t)NB_H * N_NODES * 2;       // 10.24 MB
    u8* hW      = (u8*)w; w += (size_t)N_NODES * D;                  // 5.12 MB

    k_histfuse<<<2 * NB_H + D + 1, 1024, 0, stream>>>(src, dst, cntS, cntD,
                                                      W2, b2, Wc, Wfused, bfused,
                                                      sums, blksum);
    k_degbase<<<DS_NB + BASE_NB, 256, 0, stream>>>(cntS, cntD, deg_out, deg_in,
                                                   blksum, baseDelta);
    k_scangemm<<<SCAN_NB + 625, 256, 0, stream>>>(deg_in, blksum, offsets, gid, bounds,
                                                  feat, W1, deg_out, hW);
    k_place<<<NB_H, 1024, 0, stream>>>(src, dst, offsets, baseDelta, csr);
    k_spmm1<<<2048, 256, 0, stream>>>(hW, csr, offsets, deg_out, deg_in, b1, h1s);
    k_spmm2pool<<<2048, 256, 0, stream>>>(h1s, csr, offsets, deg_in, gid, sums);
    k_out<<<N_GRAPHS, 64, 0, stream>>>(sums, bounds, Wfused, bfused, bc, out);
}

// Round 22
// 130.817 us; speedup vs baseline: 1.0128x; 1.0128x over previous
//
#include <hip/hip_runtime.h>
#include <hip/hip_fp16.h>

#define N_NODES   40000
#define N_EDGES   640000
#define D         128
#define N_CLASSES 40
#define N_GRAPHS  128

#define SCAN_CHUNK 2048
#define SCAN_NB    ((N_NODES + SCAN_CHUNK - 1) / SCAN_CHUNK)   // 20

#define NB_H    128
#define CHUNK_H (N_EDGES / NB_H)        // 5000 (< 65536 so u16 counts can't overflow)
#define NWORDS  (N_NODES / 2)           // 20000 u32 words of packed u16 counters
#define DS_NB   ((NWORDS + 255) / 256)  // 79
#define BASE_NB ((N_NODES + 255) / 256) // 157

#define SP2_NPW   5                     // ceil(40000 / 8192) contiguous nodes per wave

typedef unsigned int uint;
typedef unsigned short u16;
typedef unsigned char u8;
typedef _Float16 f16x8 __attribute__((ext_vector_type(8)));
typedef float f32x4 __attribute__((ext_vector_type(4)));
typedef float f32x2 __attribute__((ext_vector_type(2)));

// ------ hist (blocks 0..255) + DISTRIBUTED fuse (blocks 256..384, one k each) ---
__global__ __launch_bounds__(1024) void k_histfuse(const int* __restrict__ src,
                                                   const int* __restrict__ dst,
                                                   uint* __restrict__ cntS,
                                                   uint* __restrict__ cntD,
                                                   const float* __restrict__ W2,
                                                   const float* __restrict__ b2,
                                                   const float* __restrict__ Wc,
                                                   float* __restrict__ Wfused,
                                                   float* __restrict__ bfused,
                                                   float* __restrict__ sums,
                                                   uint* __restrict__ blksum) {
    __shared__ uint h[NWORDS];          // 80 KB
    const int bg = blockIdx.x, t = threadIdx.x;
    if (bg >= 2 * NB_H) {
        // ---- fuse branch, one k-row per block (129 blocks, latency overlapped) --
        const int k = bg - 2 * NB_H;    // 0..128; 128 = b2 row
        if (k < N_GRAPHS && t < D) sums[k * D + t] = 0.f;
        if (k == 0 && t < 32) blksum[t] = 0;
        if (t < N_CLASSES) {
            const float* row = (k < D) ? &W2[k * D] : b2;
            float s = 0.f;
            #pragma unroll 8
            for (int j = 0; j < D; ++j) s += row[j] * Wc[j * N_CLASSES + t];
            if (k < D) Wfused[k * N_CLASSES + t] = s;
            else bfused[t] = s;
        }
        return;
    }
    const int b = (bg < NB_H) ? bg : bg - NB_H;
    const int* __restrict__ idx = (bg < NB_H) ? src : dst;
    uint* __restrict__ cnt = (bg < NB_H) ? cntS : cntD;
    for (int i = t; i < NWORDS; i += 1024) h[i] = 0;
    __syncthreads();
    const int base = b * CHUNK_H;
    for (int e = t; e < CHUNK_H; e += 1024) {
        int v = idx[base + e];
        atomicAdd(&h[v >> 1], 1u << ((v & 1) * 16));
    }
    __syncthreads();
    for (int i = t; i < NWORDS; i += 1024) cnt[(size_t)b * NWORDS + i] = h[i];
}

// ------ merged: blocks 0..78 = deg sums; 79..235 = per-chunk CSR deltas --------
__global__ __launch_bounds__(256) void k_degbase(const uint* __restrict__ cntS,
                                                 const uint* __restrict__ cntD,
                                                 uint* __restrict__ deg_out,
                                                 uint* __restrict__ deg_in,
                                                 uint* __restrict__ blksum,
                                                 u16* __restrict__ baseDelta) {
    __shared__ uint wsum[4];
    const int t = threadIdx.x;
    if (blockIdx.x < DS_NB) {
        const int w = blockIdx.x * 256 + t;
        uint tot = 0;
        if (w < NWORDS) {
            uint s0 = 0, s1 = 0, d0 = 0, d1 = 0;
            for (int bb = 0; bb < NB_H; ++bb) {
                uint cs = cntS[(size_t)bb * NWORDS + w];
                s0 += cs & 0xffffu; s1 += cs >> 16;
            }
            for (int bb = 0; bb < NB_H; ++bb) {
                uint cd = cntD[(size_t)bb * NWORDS + w];
                d0 += cd & 0xffffu; d1 += cd >> 16;
            }
            deg_out[2 * w] = s0; deg_out[2 * w + 1] = s1;
            deg_in[2 * w]  = d0; deg_in[2 * w + 1]  = d1;
            tot = d0 + d1;
        }
        #pragma unroll
        for (int off = 32; off > 0; off >>= 1) tot += __shfl_down(tot, off);
        if ((t & 63) == 0) wsum[t >> 6] = tot;
        __syncthreads();
        if (t == 0) atomicAdd(&blksum[blockIdx.x >> 2],
                              wsum[0] + wsum[1] + wsum[2] + wsum[3]);
        return;
    }
    // ---- base branch: within-node prefix over chunks (u16 deltas) ----
    int i = (blockIdx.x - DS_NB) * 256 + t;
    if (i >= N_NODES) return;
    uint run = 0;
    for (int b = 0; b < NB_H; ++b) {
        baseDelta[(size_t)b * N_NODES + i] = (u16)run;
        run += (cntD[(size_t)b * NWORDS + (i >> 1)] >> ((i & 1) * 16)) & 0xffffu;
    }
}

// ------ merged: blocks 0..19 = scan_c (offsets+bounds); 20..644 = MFMA gemm1 ----
// gemm1 epilogue emits fp8 e4m3 hW.
__global__ __launch_bounds__(256, 1) void k_scangemm(const uint* __restrict__ deg_in,
                                                     const uint* __restrict__ blksum,
                                                     uint* __restrict__ offsets,
                                                     const int* __restrict__ gid,
                                                     int* __restrict__ bounds,
                                                     const float* __restrict__ feat,
                                                     const float* __restrict__ W1,
                                                     const uint* __restrict__ deg_out,
                                                     u8* __restrict__ hW) {
    __shared__ uint wsum[4];
    const int t = threadIdx.x;
    if (blockIdx.x < SCAN_NB) {
        // ---------------- scan_c branch ----------------
        const int b = blockIdx.x;
        const int lane = t & 63, wave = t >> 6;
        uint basesum = 0;
        for (int q = 0; q < b; ++q) basesum += blksum[q];
        const int base = b * SCAN_CHUNK + t * 8;
        uint v[8];
        uint s = 0;
        #pragma unroll
        for (int j = 0; j < 8; ++j) {
            int idx = base + j;
            v[j] = (idx < N_NODES) ? deg_in[idx] : 0u;
            s += v[j];
        }
        uint inc = s;
        #pragma unroll
        for (int off = 1; off < 64; off <<= 1) {
            uint o = __shfl_up(inc, off);
            if (lane >= off) inc += o;
        }
        if (lane == 63) wsum[wave] = inc;
        __syncthreads();
        if (t < 4) {
            uint w = wsum[t];
            #pragma unroll
            for (int off = 1; off < 4; off <<= 1) {
                uint o = __shfl_up(w, off);
                if (t >= off) w += o;
            }
            wsum[t] = w;
        }
        __syncthreads();
        uint excl = inc - s + (wave ? wsum[wave - 1] : 0u) + basesum;
        #pragma unroll
        for (int j = 0; j < 8; ++j) {
            int idx = base + j;
            if (idx < N_NODES) offsets[idx] = excl;
            excl += v[j];
        }
        if (b == SCAN_NB - 1 && t == 255) offsets[N_NODES] = excl;
        for (int j = 0; j < 8; ++j) {
            int idx = base + j;
            if (idx >= N_NODES) break;
            int g = gid[idx];
            if (idx == 0) {
                for (int q = 0; q <= g; ++q) bounds[q] = 0;
            } else {
                int gp = gid[idx - 1];
                for (int q = gp + 1; q <= g; ++q) bounds[q] = idx;
            }
            if (idx == N_NODES - 1) {
                for (int q = g + 1; q <= N_GRAPHS; ++q) bounds[q] = N_NODES;
            }
        }
        return;
    }
    // ---------------- gemm1 branch ----------------
    const int wv = t >> 6, l = t & 63;
    const int kg = l >> 4;
    const int c  = l & 15;
    const int r0 = (blockIdx.x - SCAN_NB) * 64 + wv * 16;

    f16x8 B[4][8];
    #pragma unroll
    for (int ks = 0; ks < 4; ++ks) {
        #pragma unroll
        for (int nt = 0; nt < 8; ++nt) {
            const int kb = ks * 32 + kg * 8;
            const int col = nt * 16 + c;
            f16x8 b;
            #pragma unroll
            for (int i = 0; i < 8; ++i)
                b[i] = (_Float16)W1[(kb + i) * D + col];
            B[ks][nt] = b;
        }
    }

    f32x4 acc[8];
    #pragma unroll
    for (int nt = 0; nt < 8; ++nt) acc[nt] = (f32x4){0.f, 0.f, 0.f, 0.f};

    const int arow = r0 + c;
    #pragma unroll
    for (int ks = 0; ks < 4; ++ks) {
        const float4 q0 = *(const float4*)&feat[(size_t)arow * D + ks * 32 + kg * 8];
        const float4 q1 = *(const float4*)&feat[(size_t)arow * D + ks * 32 + kg * 8 + 4];
        f16x8 a;
        a[0] = (_Float16)q0.x; a[1] = (_Float16)q0.y;
        a[2] = (_Float16)q0.z; a[3] = (_Float16)q0.w;
        a[4] = (_Float16)q1.x; a[5] = (_Float16)q1.y;
        a[6] = (_Float16)q1.z; a[7] = (_Float16)q1.w;
        #pragma unroll
        for (int nt = 0; nt < 8; ++nt)
            acc[nt] = __builtin_amdgcn_mfma_f32_16x16x32_f16(a, B[ks][nt], acc[nt], 0, 0, 0);
    }

    const int rloc = kg * 4;
    float ns[4];
    #pragma unroll
    for (int r = 0; r < 4; ++r)
        ns[r] = rsqrtf(fmaxf((float)deg_out[r0 + rloc + r], 1.f));
    #pragma unroll
    for (int nt = 0; nt < 8; ++nt) {
        #pragma unroll
        for (int r = 0; r < 4; ++r) {
            float v = acc[nt][r] * ns[r];
            int pk = __builtin_amdgcn_cvt_pk_fp8_f32(v, v, 0, false);
            hW[(size_t)(r0 + rloc + r) * D + nt * 16 + c] = (u8)pk;
        }
    }
}

// ------ CSR place via LDS rank cursors (no global atomics) ------
__global__ __launch_bounds__(1024) void k_place(const int* __restrict__ src,
                                                const int* __restrict__ dst,
                                                const uint* __restrict__ offsets,
                                                const u16* __restrict__ baseDelta,
                                                int* __restrict__ csr) {
    __shared__ uint rk[NWORDS];         // 80 KB, packed u16 ranks
    const int b = blockIdx.x, t = threadIdx.x;
    for (int i = t; i < NWORDS; i += 1024) rk[i] = 0;
    __syncthreads();
    const int base = b * CHUNK_H;
    for (int e = t; e < CHUNK_H; e += 1024) {
        int d = dst[base + e];
        uint sh = (d & 1) * 16;
        uint old = atomicAdd(&rk[d >> 1], 1u << sh);
        uint r = (old >> sh) & 0xffffu;
        csr[offsets[d] + baseDelta[(size_t)b * N_NODES + d] + r] = src[base + e];
    }
}

// ------- SpMM layer 1 (fp8 gather, fp32 accum) -> fp8 e4m3 output --------------
__global__ __launch_bounds__(256) void k_spmm1(const u8* __restrict__ X,
                                               const int* __restrict__ csr_src,
                                               const uint* __restrict__ offsets,
                                               const uint* __restrict__ deg_out,
                                               const uint* __restrict__ deg_in,
                                               const float* __restrict__ b1,
                                               ushort* __restrict__ outp) {
    const int lane = threadIdx.x & 63;
    const ushort* __restrict__ Xr = (const ushort*)X;     // row = 64 fp8-pairs
    int gw = (blockIdx.x * blockDim.x + threadIdx.x) >> 6;
    int nw = (gridDim.x * blockDim.x) >> 6;
    for (int i = gw; i < N_NODES; i += nw) {
        uint e = offsets[i], e1 = offsets[i + 1];
        f32x2 acc = {0.f, 0.f};
        for (; e + 4 <= e1; e += 4) {
            int s0 = csr_src[e], s1 = csr_src[e + 1];
            int s2 = csr_src[e + 2], s3 = csr_src[e + 3];
            f32x2 v0 = __builtin_amdgcn_cvt_pk_f32_fp8(Xr[(size_t)s0 * 64 + lane], false);
            f32x2 v1 = __builtin_amdgcn_cvt_pk_f32_fp8(Xr[(size_t)s1 * 64 + lane], false);
            f32x2 v2 = __builtin_amdgcn_cvt_pk_f32_fp8(Xr[(size_t)s2 * 64 + lane], false);
            f32x2 v3 = __builtin_amdgcn_cvt_pk_f32_fp8(Xr[(size_t)s3 * 64 + lane], false);
            acc += (v0 + v1) + (v2 + v3);
        }
        for (; e < e1; ++e) {
            int s = csr_src[e];
            acc += __builtin_amdgcn_cvt_pk_f32_fp8(Xr[(size_t)s * 64 + lane], false);
        }
        float nd = rsqrtf(fmaxf((float)deg_in[i], 1.f));
        float ns = rsqrtf(fmaxf((float)deg_out[i], 1.f));
        float2 b = *(const float2*)&b1[lane * 2];
        float rx = fmaxf(acc[0] * nd + b.x, 0.f) * ns;
        float ry = fmaxf(acc[1] * nd + b.y, 0.f) * ns;
        int pk = __builtin_amdgcn_cvt_pk_fp8_f32(rx, ry, 0, false);  // OCP e4m3
        outp[(size_t)i * 64 + lane] = (ushort)pk;
    }
}

// ------- SpMM layer 2 (fp8 gather, fp32 accum) fused with pooling --------------
__global__ __launch_bounds__(256) void k_spmm2pool(const ushort* __restrict__ X16,
                                                   const int* __restrict__ csr_src,
                                                   const uint* __restrict__ offsets,
                                                   const uint* __restrict__ deg_in,
                                                   const int* __restrict__ gid,
                                                   float* __restrict__ sums) {
    const int lane = threadIdx.x & 63;
    const int w = (blockIdx.x * blockDim.x + threadIdx.x) >> 6;
    int n0 = w * SP2_NPW;
    if (n0 >= N_NODES) return;
    int n1 = n0 + SP2_NPW; if (n1 > N_NODES) n1 = N_NODES;
    f32x2 seg = {0.f, 0.f};
    int cur = gid[n0];
    for (int i = n0; i < n1; ++i) {
        int g = gid[i];
        if (g != cur) {
            atomicAdd(&sums[cur * D + 2 * lane], seg[0]);
            atomicAdd(&sums[cur * D + 2 * lane + 1], seg[1]);
            seg[0] = 0.f; seg[1] = 0.f; cur = g;
        }
        uint e = offsets[i], e1 = offsets[i + 1];
        f32x2 acc = {0.f, 0.f};
        for (; e + 4 <= e1; e += 4) {
            int s0 = csr_src[e], s1 = csr_src[e + 1];
            int s2 = csr_src[e + 2], s3 = csr_src[e + 3];
            f32x2 v0 = __builtin_amdgcn_cvt_pk_f32_fp8(X16[(size_t)s0 * 64 + lane], false);
            f32x2 v1 = __builtin_amdgcn_cvt_pk_f32_fp8(X16[(size_t)s1 * 64 + lane], false);
            f32x2 v2 = __builtin_amdgcn_cvt_pk_f32_fp8(X16[(size_t)s2 * 64 + lane], false);
            f32x2 v3 = __builtin_amdgcn_cvt_pk_f32_fp8(X16[(size_t)s3 * 64 + lane], false);
            acc += (v0 + v1) + (v2 + v3);
        }
        for (; e < e1; ++e) {
            int s = csr_src[e];
            acc += __builtin_amdgcn_cvt_pk_f32_fp8(X16[(size_t)s * 64 + lane], false);
        }
        float nd = rsqrtf(fmaxf((float)deg_in[i], 1.f));
        seg[0] += acc[0] * nd;
        seg[1] += acc[1] * nd;
    }
    atomicAdd(&sums[cur * D + 2 * lane], seg[0]);
    atomicAdd(&sums[cur * D + 2 * lane + 1], seg[1]);
}

// ---------------- per-graph classifier matvec ----------------
__global__ __launch_bounds__(64) void k_out(const float* __restrict__ sums,
                                            const int* __restrict__ bounds,
                                            const float* __restrict__ Wfused,
                                            const float* __restrict__ bfused,
                                            const float* __restrict__ bc,
                                            float* __restrict__ out) {
    int g = blockIdx.x, c = threadIdx.x;
    if (c >= N_CLASSES) return;
    int cnt = bounds[g + 1] - bounds[g];
    float inv = (cnt > 0) ? 1.f / (float)cnt : 0.f;
    float s = 0.f;
    #pragma unroll 8
    for (int k = 0; k < D; ++k) s += sums[g * D + k] * Wfused[k * N_CLASSES + c];
    out[g * N_CLASSES + c] = s * inv + (cnt > 0 ? bfused[c] : 0.f) + bc[c];
}

extern "C" void kernel_launch(void* const* d_in, const int* in_sizes, int n_in,
                              void* d_out, int out_size, void* d_ws, size_t ws_size,
                              hipStream_t stream) {
    const float* feat = (const float*)d_in[0];
    const float* W1   = (const float*)d_in[1];
    const float* b1   = (const float*)d_in[2];
    const float* W2   = (const float*)d_in[3];
    const float* b2   = (const float*)d_in[4];
    const float* Wc   = (const float*)d_in[5];
    const float* bc   = (const float*)d_in[6];
    const int*   src  = (const int*)d_in[7];
    const int*   dst  = (const int*)d_in[8];
    const int*   gid  = (const int*)d_in[9];
    float* out = (float*)d_out;

    // Dispatch order: histfuse, degbase, scangemm(hW), place(csr),
    // spmm1(h1s), spmm2pool, out.
    // Aliasing: csr over cntS (cntS last read: degbase); h1s over cntD (cntD
    // last read: degbase). hW disjoint (written by scangemm, before place).
    char* w = (char*)d_ws;
    uint* deg_out = (uint*)w; w += (size_t)N_NODES * 4;
    uint* deg_in  = (uint*)w; w += (size_t)N_NODES * 4;
    uint* offsets = (uint*)w; w += (size_t)(N_NODES + 4) * 4;
    int*  bounds  = (int*)w;  w += 132 * 4;
    uint* blksum  = (uint*)w; w += 32 * 4;
    float* Wfused = (float*)w; w += (size_t)D * N_CLASSES * 4;
    float* bfused = (float*)w; w += 64 * 4;
    float* sums   = (float*)w; w += (size_t)N_GRAPHS * D * 4;
    char* regA = w; w += (size_t)NB_H * NWORDS * 4;                  // 10.24 MB
    uint* cntS  = (uint*)regA;
    int*  csr   = (int*)regA;        // 2.56 MB, lives after degbase
    char* regB = w; w += (size_t)NB_H * NWORDS * 4;                  // 10.24 MB
    uint* cntD  = (uint*)regB;
    ushort* h1s = (ushort*)regB;     // fp8 pairs: 5.12 MB, lives after degbase
    u16* baseDelta = (u16*)w; w += (size_t)NB_H * N_NODES * 2;       // 10.24 MB
    u8* hW      = (u8*)w; w += (size_t)N_NODES * D;                  // 5.12 MB

    k_histfuse<<<2 * NB_H + D + 1, 1024, 0, stream>>>(src, dst, cntS, cntD,
                                                      W2, b2, Wc, Wfused, bfused,
                                                      sums, blksum);
    k_degbase<<<DS_NB + BASE_NB, 256, 0, stream>>>(cntS, cntD, deg_out, deg_in,
                                                   blksum, baseDelta);
    k_scangemm<<<SCAN_NB + 625, 256, 0, stream>>>(deg_in, blksum, offsets, gid, bounds,
                                                  feat, W1, deg_out, hW);
    k_place<<<NB_H, 1024, 0, stream>>>(src, dst, offsets, baseDelta, csr);
    k_spmm1<<<2048, 256, 0, stream>>>(hW, csr, offsets, deg_out, deg_in, b1, h1s);
    k_spmm2pool<<<2048, 256, 0, stream>>>(h1s, csr, offsets, deg_in, gid, sums);
    k_out<<<N_GRAPHS, 64, 0, stream>>>(sums, bounds, Wfused, bfused, bc, out);
}